// Round 6
// baseline (105.414 us; speedup 1.0000x reference)
//
#include <hip/hip_runtime.h>
#include <math.h>

constexpr int E_EDGES = 4194304;
constexpr int N_PATCH = 524288;
constexpr int N_POSES = 2048;
constexpr float EPS_W = 1e-8f;

typedef int   iv4 __attribute__((ext_vector_type(4)));
typedef float fv4 __attribute__((ext_vector_type(4)));
typedef float fv2 __attribute__((ext_vector_type(2)));

// ---- prep 1: fold r/theta/phi trig into an f32x4 local_src table (16B/patch) ----
// f32 is mandatory: f16 rounding flips atan2's branch cut (round-5 failure, absmax=2pi*sy).
__global__ __launch_bounds__(256) void prep_patches(
    const fv2*  __restrict__ pc_rt,    // N_PATCH x (r,theta)
    const float* __restrict__ elev,    // N_PATCH
    fv4*        __restrict__ local4)   // N_PATCH x (lx,ly,lz,0)
{
    const int j = blockIdx.x * blockDim.x + threadIdx.x;
    if (j >= N_PATCH) return;
    const fv2 pc = pc_rt[j];
    const float phi = elev[j];
    float sphi, cphi, sth, cth;
    __sincosf(phi,  &sphi, &cphi);
    __sincosf(pc.y, &sth,  &cth);
    const float rcp = pc.x * cphi;
    fv4 o;
    o.x = rcp * cth;
    o.y = rcp * sth;
    o.z = pc.x * sphi;
    o.w = 0.0f;
    local4[j] = o;
}

// ---- prep 2: pad poses 7 -> 8 floats (2x dwordx4) ----
__global__ __launch_bounds__(256) void prep_poses(
    const float* __restrict__ poses, fv4* __restrict__ poses8)
{
    const int j = blockIdx.x * blockDim.x + threadIdx.x;
    if (j >= N_POSES) return;
    const float* p = poses + (size_t)j * 7;
    fv4 a, b;
    a.x = p[0]; a.y = p[1]; a.z = p[2]; a.w = p[3];   // px py pz qx
    b.x = p[4]; b.y = p[5]; b.z = p[6]; b.w = 0.0f;   // qy qz qw -
    poses8[2 * j]     = a;
    poses8[2 * j + 1] = b;
}

// ---- main: 8 edges/thread; poses in LDS; 1 divergent VMEM gather per edge ----
__global__ __launch_bounds__(256, 2) void ba_main(
    const fv4*  __restrict__ poses8,
    const fv4*  __restrict__ local4,
    const float* __restrict__ scale,
    const fv4*  __restrict__ baseline4,
    const fv4*  __restrict__ weights4,
    const iv4*  __restrict__ patch_idx4,
    const iv4*  __restrict__ src_idx4,
    const iv4*  __restrict__ tgt_idx4,
    fv4*        __restrict__ out4)
{
    __shared__ fv4 sposes[N_POSES * 2];   // 64 KB
#pragma unroll
    for (int k = 0; k < (N_POSES * 2) / 256; ++k)
        sposes[k * 256 + threadIdx.x] = poses8[k * 256 + threadIdx.x];
    __syncthreads();

    const int t = blockIdx.x * blockDim.x + threadIdx.x;  // one thread = 8 edges

    const iv4 pi0 = __builtin_nontemporal_load(patch_idx4 + 2 * t);
    const iv4 pi1 = __builtin_nontemporal_load(patch_idx4 + 2 * t + 1);
    const iv4 si0 = __builtin_nontemporal_load(src_idx4 + 2 * t);
    const iv4 si1 = __builtin_nontemporal_load(src_idx4 + 2 * t + 1);
    const iv4 ti0 = __builtin_nontemporal_load(tgt_idx4 + 2 * t);
    const iv4 ti1 = __builtin_nontemporal_load(tgt_idx4 + 2 * t + 1);

    fv4 bl[4], w[4];
#pragma unroll
    for (int k = 0; k < 4; ++k) {
        bl[k] = __builtin_nontemporal_load(baseline4 + 4 * t + k);
        w[k]  = __builtin_nontemporal_load(weights4 + 4 * t + k);
    }

    int pia[8], sia[8], gia[8];
#pragma unroll
    for (int i = 0; i < 4; ++i) {
        pia[i]     = ((const int*)&pi0)[i];
        pia[i + 4] = ((const int*)&pi1)[i];
        sia[i]     = ((const int*)&si0)[i];
        sia[i + 4] = ((const int*)&si1)[i];
        gia[i]     = ((const int*)&ti0)[i];
        gia[i + 4] = ((const int*)&ti1)[i];
    }

    // issue all 8 divergent table gathers up front (the only VMEM gathers left)
    fv4 L[8];
#pragma unroll
    for (int i = 0; i < 8; ++i) L[i] = local4[pia[i]];
    __builtin_amdgcn_sched_barrier(0);

    const float sx = scale[0];
    const float sy = scale[1];

    float rx[8], ry[8];
#pragma unroll
    for (int i = 0; i < 8; ++i) {
        const float lx = L[i].x, ly = L[i].y, lz = L[i].z;

        const fv4 S0 = sposes[2 * sia[i]];
        const fv4 S1 = sposes[2 * sia[i] + 1];
        const fv4 T0 = sposes[2 * gia[i]];
        const fv4 T1 = sposes[2 * gia[i] + 1];

        const float qx = S0.w, qy = S1.x, qz = S1.y, qw = S1.z;
        const float t0 = 2.0f * (qy * lz - qz * ly);
        const float t1 = 2.0f * (qz * lx - qx * lz);
        const float t2 = 2.0f * (qx * ly - qy * lx);
        const float gx = lx + qw * t0 + (qy * t2 - qz * t1) + S0.x;
        const float gy = ly + qw * t1 + (qz * t0 - qx * t2) + S0.y;
        const float gz = lz + qw * t2 + (qx * t1 - qy * t0) + S0.z;

        const float dx = gx - T0.x;
        const float dy = gy - T0.y;
        const float dz = gz - T0.z;
        const float uqx = -T0.w, uqy = -T1.x, uqz = -T1.y, uqw = T1.z;

        const float u0 = 2.0f * (uqy * dz - uqz * dy);
        const float u1 = 2.0f * (uqz * dx - uqx * dz);
        const float u2 = 2.0f * (uqx * dy - uqy * dx);
        const float ox = dx + uqw * u0 + (uqy * u2 - uqz * u1);
        const float oy = dy + uqw * u1 + (uqz * u0 - uqx * u2);
        const float oz = dz + uqw * u2 + (uqx * u1 - uqy * u0);

        rx[i] = sqrtf(ox * ox + oy * oy + oz * oz) * sx;
        ry[i] = atan2f(oy, ox) * sy;
    }

#pragma unroll
    for (int k = 0; k < 4; ++k) {
        fv4 o;
        o.x = (rx[2 * k]     - bl[k].x) * sqrtf(w[k].x + EPS_W);
        o.y = (ry[2 * k]     - bl[k].y) * sqrtf(w[k].y + EPS_W);
        o.z = (rx[2 * k + 1] - bl[k].z) * sqrtf(w[k].z + EPS_W);
        o.w = (ry[2 * k + 1] - bl[k].w) * sqrtf(w[k].w + EPS_W);
        __builtin_nontemporal_store(o, out4 + 4 * t + k);
    }
}

// ---- fallback (round-3 proven kernel) if ws is too small ----
__global__ __launch_bounds__(256, 4) void ba_fallback(
    const float* __restrict__ poses,
    const float* __restrict__ pc_rt,
    const float* __restrict__ elev,
    const float* __restrict__ scale,
    const fv4*   __restrict__ baseline4,
    const fv4*   __restrict__ weights4,
    const iv4*   __restrict__ patch_idx4,
    const iv4*   __restrict__ inv_idx4,
    const iv4*   __restrict__ src_idx4,
    const iv4*   __restrict__ tgt_idx4,
    fv4*         __restrict__ out4)
{
    const float sx = scale[0];
    const float sy = scale[1];
    const int t = blockIdx.x * blockDim.x + threadIdx.x;

    const iv4 pi = __builtin_nontemporal_load(patch_idx4 + t);
    const iv4 ii = __builtin_nontemporal_load(inv_idx4 + t);
    const iv4 si = __builtin_nontemporal_load(src_idx4 + t);
    const iv4 ti = __builtin_nontemporal_load(tgt_idx4 + t);

    const fv4 bl01 = __builtin_nontemporal_load(baseline4 + 2 * t);
    const fv4 bl23 = __builtin_nontemporal_load(baseline4 + 2 * t + 1);
    const fv4 w01  = __builtin_nontemporal_load(weights4 + 2 * t);
    const fv4 w23  = __builtin_nontemporal_load(weights4 + 2 * t + 1);

    float rx[4], ry[4];
#pragma unroll
    for (int i = 0; i < 4; ++i) {
        const int p = ((const int*)&pi)[i];
        const int v = ((const int*)&ii)[i];
        const int s = ((const int*)&si)[i];
        const int g = ((const int*)&ti)[i];
        const float r  = pc_rt[2 * (size_t)p];
        const float th = pc_rt[2 * (size_t)p + 1];
        const float phi = elev[v];
        const float* Pp = poses + (size_t)s * 7;
        const float* Tp = poses + (size_t)g * 7;

        float sphi, cphi, sth, cth;
        __sincosf(phi, &sphi, &cphi);
        __sincosf(th,  &sth,  &cth);
        const float rcp = r * cphi;
        const float lx = rcp * cth, ly = rcp * sth, lz = r * sphi;

        const float qx = Pp[3], qy = Pp[4], qz = Pp[5], qw = Pp[6];
        const float t0 = 2.0f * (qy * lz - qz * ly);
        const float t1 = 2.0f * (qz * lx - qx * lz);
        const float t2 = 2.0f * (qx * ly - qy * lx);
        const float gx = lx + qw * t0 + (qy * t2 - qz * t1) + Pp[0];
        const float gy = ly + qw * t1 + (qz * t0 - qx * t2) + Pp[1];
        const float gz = lz + qw * t2 + (qx * t1 - qy * t0) + Pp[2];

        const float dx = gx - Tp[0], dy = gy - Tp[1], dz = gz - Tp[2];
        const float uqx = -Tp[3], uqy = -Tp[4], uqz = -Tp[5], uqw = Tp[6];
        const float u0 = 2.0f * (uqy * dz - uqz * dy);
        const float u1 = 2.0f * (uqz * dx - uqx * dz);
        const float u2 = 2.0f * (uqx * dy - uqy * dx);
        const float ox = dx + uqw * u0 + (uqy * u2 - uqz * u1);
        const float oy = dy + uqw * u1 + (uqz * u0 - uqx * u2);
        const float oz = dz + uqw * u2 + (uqx * u1 - uqy * u0);

        rx[i] = sqrtf(ox * ox + oy * oy + oz * oz) * sx;
        ry[i] = atan2f(oy, ox) * sy;
    }

    fv4 o01, o23;
    o01.x = (rx[0] - bl01.x) * sqrtf(w01.x + EPS_W);
    o01.y = (ry[0] - bl01.y) * sqrtf(w01.y + EPS_W);
    o01.z = (rx[1] - bl01.z) * sqrtf(w01.z + EPS_W);
    o01.w = (ry[1] - bl01.w) * sqrtf(w01.w + EPS_W);
    o23.x = (rx[2] - bl23.x) * sqrtf(w23.x + EPS_W);
    o23.y = (ry[2] - bl23.y) * sqrtf(w23.y + EPS_W);
    o23.z = (rx[3] - bl23.z) * sqrtf(w23.z + EPS_W);
    o23.w = (ry[3] - bl23.w) * sqrtf(w23.w + EPS_W);

    __builtin_nontemporal_store(o01, out4 + 2 * t);
    __builtin_nontemporal_store(o23, out4 + 2 * t + 1);
}

extern "C" void kernel_launch(void* const* d_in, const int* in_sizes, int n_in,
                              void* d_out, int out_size, void* d_ws, size_t ws_size,
                              hipStream_t stream) {
    const float* poses    = (const float*)d_in[0];
    const float* pc_rt    = (const float*)d_in[1];
    const float* elev     = (const float*)d_in[2];
    const float* scale    = (const float*)d_in[3];
    const fv4*   baseline = (const fv4*)d_in[4];
    const fv4*   weights4 = (const fv4*)d_in[5];
    const iv4*   patch_i  = (const iv4*)d_in[6];
    const iv4*   inv_i    = (const iv4*)d_in[7];
    const iv4*   src_i    = (const iv4*)d_in[8];
    const iv4*   tgt_i    = (const iv4*)d_in[9];
    fv4*         out      = (fv4*)d_out;

    const size_t local_bytes  = (size_t)N_PATCH * 16;  // f32x4 table
    const size_t poses8_bytes = (size_t)N_POSES * 32;

    if (ws_size >= local_bytes + poses8_bytes) {
        fv4* local4 = (fv4*)d_ws;
        fv4* poses8 = (fv4*)((char*)d_ws + local_bytes);

        hipLaunchKernelGGL(prep_patches, dim3(N_PATCH / 256), dim3(256), 0, stream,
                           (const fv2*)pc_rt, elev, local4);
        hipLaunchKernelGGL(prep_poses, dim3(N_POSES / 256), dim3(256), 0, stream,
                           poses, poses8);
        const int threads = E_EDGES / 8;  // 524,288
        hipLaunchKernelGGL(ba_main, dim3(threads / 256), dim3(256), 0, stream,
                           (const fv4*)poses8, (const fv4*)local4, scale,
                           baseline, weights4, patch_i, src_i, tgt_i, out);
    } else {
        const int threads = E_EDGES / 4;
        hipLaunchKernelGGL(ba_fallback, dim3(threads / 256), dim3(256), 0, stream,
                           poses, pc_rt, elev, scale, baseline, weights4,
                           patch_i, inv_i, src_i, tgt_i, out);
    }
}

// Round 7
// 82.988 us; speedup vs baseline: 1.2702x; 1.2702x over previous
//
#include <hip/hip_runtime.h>
#include <math.h>

constexpr int E_EDGES = 4194304;
constexpr int N_PATCH = 524288;
constexpr int N_POSES = 2048;
constexpr float EPS_W = 1e-8f;

typedef int   iv4 __attribute__((ext_vector_type(4)));
typedef float fv4 __attribute__((ext_vector_type(4)));
typedef float fv2 __attribute__((ext_vector_type(2)));

// ---- prep 1: fold r/theta/phi trig into an f32x4 local_src table (16B/patch) ----
// f32 is mandatory: f16 rounding flips atan2's branch cut (round-5 failure, absmax=2pi*sy).
__global__ __launch_bounds__(256) void prep_patches(
    const fv2*  __restrict__ pc_rt,    // N_PATCH x (r,theta)
    const float* __restrict__ elev,    // N_PATCH
    fv4*        __restrict__ local4)   // N_PATCH x (lx,ly,lz,0)
{
    const int j = blockIdx.x * blockDim.x + threadIdx.x;
    if (j >= N_PATCH) return;
    const fv2 pc = pc_rt[j];
    const float phi = elev[j];
    float sphi, cphi, sth, cth;
    __sincosf(phi,  &sphi, &cphi);
    __sincosf(pc.y, &sth,  &cth);
    const float rcp = pc.x * cphi;
    fv4 o;
    o.x = rcp * cth;
    o.y = rcp * sth;
    o.z = pc.x * sphi;
    o.w = 0.0f;
    local4[j] = o;
}

// ---- prep 2: pad poses 7 -> 8 floats ----
__global__ __launch_bounds__(256) void prep_poses(
    const float* __restrict__ poses, fv4* __restrict__ poses8)
{
    const int j = blockIdx.x * blockDim.x + threadIdx.x;
    if (j >= N_POSES) return;
    const float* p = poses + (size_t)j * 7;
    fv4 a, b;
    a.x = p[0]; a.y = p[1]; a.z = p[2]; a.w = p[3];   // px py pz qx
    b.x = p[4]; b.y = p[5]; b.z = p[6]; b.w = 0.0f;   // qy qz qw -
    poses8[2 * j]     = a;
    poses8[2 * j + 1] = b;
}

// ---- main: 512 thr/block (2 blocks/CU with 64KB LDS -> 16 waves/CU),
//      4 edges/thread, poses in LDS, 1 divergent VMEM gather per edge ----
__global__ __launch_bounds__(512, 4) void ba_main(
    const fv4*  __restrict__ poses8,
    const fv4*  __restrict__ local4,
    const float* __restrict__ scale,
    const fv4*  __restrict__ baseline4,
    const fv4*  __restrict__ weights4,
    const iv4*  __restrict__ patch_idx4,
    const iv4*  __restrict__ src_idx4,
    const iv4*  __restrict__ tgt_idx4,
    fv4*        __restrict__ out4)
{
    __shared__ fv4 sposes[N_POSES * 2];   // 64 KB
#pragma unroll
    for (int k = 0; k < (N_POSES * 2) / 512; ++k)
        sposes[k * 512 + threadIdx.x] = poses8[k * 512 + threadIdx.x];
    __syncthreads();

    const int t = blockIdx.x * blockDim.x + threadIdx.x;  // one thread = 4 edges

    const iv4 pi = __builtin_nontemporal_load(patch_idx4 + t);
    const iv4 si = __builtin_nontemporal_load(src_idx4 + t);
    const iv4 ti = __builtin_nontemporal_load(tgt_idx4 + t);

    const fv4 bl01 = __builtin_nontemporal_load(baseline4 + 2 * t);
    const fv4 bl23 = __builtin_nontemporal_load(baseline4 + 2 * t + 1);
    const fv4 w01  = __builtin_nontemporal_load(weights4 + 2 * t);
    const fv4 w23  = __builtin_nontemporal_load(weights4 + 2 * t + 1);

    int pia[4], sia[4], gia[4];
#pragma unroll
    for (int i = 0; i < 4; ++i) {
        pia[i] = ((const int*)&pi)[i];
        sia[i] = ((const int*)&si)[i];
        gia[i] = ((const int*)&ti)[i];
    }

    // issue all 4 divergent table gathers up front (the only VMEM gathers left)
    fv4 L[4];
#pragma unroll
    for (int i = 0; i < 4; ++i) L[i] = local4[pia[i]];
    __builtin_amdgcn_sched_barrier(0);

    const float sx = scale[0];
    const float sy = scale[1];

    float rx[4], ry[4];
#pragma unroll
    for (int i = 0; i < 4; ++i) {
        const float lx = L[i].x, ly = L[i].y, lz = L[i].z;

        const fv4 S0 = sposes[2 * sia[i]];
        const fv4 S1 = sposes[2 * sia[i] + 1];
        const fv4 T0 = sposes[2 * gia[i]];
        const fv4 T1 = sposes[2 * gia[i] + 1];

        const float qx = S0.w, qy = S1.x, qz = S1.y, qw = S1.z;
        const float t0 = 2.0f * (qy * lz - qz * ly);
        const float t1 = 2.0f * (qz * lx - qx * lz);
        const float t2 = 2.0f * (qx * ly - qy * lx);
        const float gx = lx + qw * t0 + (qy * t2 - qz * t1) + S0.x;
        const float gy = ly + qw * t1 + (qz * t0 - qx * t2) + S0.y;
        const float gz = lz + qw * t2 + (qx * t1 - qy * t0) + S0.z;

        const float dx = gx - T0.x;
        const float dy = gy - T0.y;
        const float dz = gz - T0.z;
        const float uqx = -T0.w, uqy = -T1.x, uqz = -T1.y, uqw = T1.z;

        const float u0 = 2.0f * (uqy * dz - uqz * dy);
        const float u1 = 2.0f * (uqz * dx - uqx * dz);
        const float u2 = 2.0f * (uqx * dy - uqy * dx);
        const float ox = dx + uqw * u0 + (uqy * u2 - uqz * u1);
        const float oy = dy + uqw * u1 + (uqz * u0 - uqx * u2);
        const float oz = dz + uqw * u2 + (uqx * u1 - uqy * u0);

        rx[i] = sqrtf(ox * ox + oy * oy + oz * oz) * sx;
        ry[i] = atan2f(oy, ox) * sy;
    }

    // plain stores: partial-line pairs combine in L2 (NT stores caused 2x write amp)
    fv4 o01, o23;
    o01.x = (rx[0] - bl01.x) * sqrtf(w01.x + EPS_W);
    o01.y = (ry[0] - bl01.y) * sqrtf(w01.y + EPS_W);
    o01.z = (rx[1] - bl01.z) * sqrtf(w01.z + EPS_W);
    o01.w = (ry[1] - bl01.w) * sqrtf(w01.w + EPS_W);
    o23.x = (rx[2] - bl23.x) * sqrtf(w23.x + EPS_W);
    o23.y = (ry[2] - bl23.y) * sqrtf(w23.y + EPS_W);
    o23.z = (rx[3] - bl23.z) * sqrtf(w23.z + EPS_W);
    o23.w = (ry[3] - bl23.w) * sqrtf(w23.w + EPS_W);
    out4[2 * t]     = o01;
    out4[2 * t + 1] = o23;
}

// ---- fallback (round-3 proven kernel) if ws is too small ----
__global__ __launch_bounds__(256, 4) void ba_fallback(
    const float* __restrict__ poses,
    const float* __restrict__ pc_rt,
    const float* __restrict__ elev,
    const float* __restrict__ scale,
    const fv4*   __restrict__ baseline4,
    const fv4*   __restrict__ weights4,
    const iv4*   __restrict__ patch_idx4,
    const iv4*   __restrict__ inv_idx4,
    const iv4*   __restrict__ src_idx4,
    const iv4*   __restrict__ tgt_idx4,
    fv4*         __restrict__ out4)
{
    const float sx = scale[0];
    const float sy = scale[1];
    const int t = blockIdx.x * blockDim.x + threadIdx.x;

    const iv4 pi = __builtin_nontemporal_load(patch_idx4 + t);
    const iv4 ii = __builtin_nontemporal_load(inv_idx4 + t);
    const iv4 si = __builtin_nontemporal_load(src_idx4 + t);
    const iv4 ti = __builtin_nontemporal_load(tgt_idx4 + t);

    const fv4 bl01 = __builtin_nontemporal_load(baseline4 + 2 * t);
    const fv4 bl23 = __builtin_nontemporal_load(baseline4 + 2 * t + 1);
    const fv4 w01  = __builtin_nontemporal_load(weights4 + 2 * t);
    const fv4 w23  = __builtin_nontemporal_load(weights4 + 2 * t + 1);

    float rx[4], ry[4];
#pragma unroll
    for (int i = 0; i < 4; ++i) {
        const int p = ((const int*)&pi)[i];
        const int v = ((const int*)&ii)[i];
        const int s = ((const int*)&si)[i];
        const int g = ((const int*)&ti)[i];
        const float r  = pc_rt[2 * (size_t)p];
        const float th = pc_rt[2 * (size_t)p + 1];
        const float phi = elev[v];
        const float* Pp = poses + (size_t)s * 7;
        const float* Tp = poses + (size_t)g * 7;

        float sphi, cphi, sth, cth;
        __sincosf(phi, &sphi, &cphi);
        __sincosf(th,  &sth,  &cth);
        const float rcp = r * cphi;
        const float lx = rcp * cth, ly = rcp * sth, lz = r * sphi;

        const float qx = Pp[3], qy = Pp[4], qz = Pp[5], qw = Pp[6];
        const float t0 = 2.0f * (qy * lz - qz * ly);
        const float t1 = 2.0f * (qz * lx - qx * lz);
        const float t2 = 2.0f * (qx * ly - qy * lx);
        const float gx = lx + qw * t0 + (qy * t2 - qz * t1) + Pp[0];
        const float gy = ly + qw * t1 + (qz * t0 - qx * t2) + Pp[1];
        const float gz = lz + qw * t2 + (qx * t1 - qy * t0) + Pp[2];

        const float dx = gx - Tp[0], dy = gy - Tp[1], dz = gz - Tp[2];
        const float uqx = -Tp[3], uqy = -Tp[4], uqz = -Tp[5], uqw = Tp[6];
        const float u0 = 2.0f * (uqy * dz - uqz * dy);
        const float u1 = 2.0f * (uqz * dx - uqx * dz);
        const float u2 = 2.0f * (uqx * dy - uqy * dx);
        const float ox = dx + uqw * u0 + (uqy * u2 - uqz * u1);
        const float oy = dy + uqw * u1 + (uqz * u0 - uqx * u2);
        const float oz = dz + uqw * u2 + (uqx * u1 - uqy * u0);

        rx[i] = sqrtf(ox * ox + oy * oy + oz * oz) * sx;
        ry[i] = atan2f(oy, ox) * sy;
    }

    fv4 o01, o23;
    o01.x = (rx[0] - bl01.x) * sqrtf(w01.x + EPS_W);
    o01.y = (ry[0] - bl01.y) * sqrtf(w01.y + EPS_W);
    o01.z = (rx[1] - bl01.z) * sqrtf(w01.z + EPS_W);
    o01.w = (ry[1] - bl01.w) * sqrtf(w01.w + EPS_W);
    o23.x = (rx[2] - bl23.x) * sqrtf(w23.x + EPS_W);
    o23.y = (ry[2] - bl23.y) * sqrtf(w23.y + EPS_W);
    o23.z = (rx[3] - bl23.z) * sqrtf(w23.z + EPS_W);
    o23.w = (ry[3] - bl23.w) * sqrtf(w23.w + EPS_W);

    out4[2 * t]     = o01;
    out4[2 * t + 1] = o23;
}

extern "C" void kernel_launch(void* const* d_in, const int* in_sizes, int n_in,
                              void* d_out, int out_size, void* d_ws, size_t ws_size,
                              hipStream_t stream) {
    const float* poses    = (const float*)d_in[0];
    const float* pc_rt    = (const float*)d_in[1];
    const float* elev     = (const float*)d_in[2];
    const float* scale    = (const float*)d_in[3];
    const fv4*   baseline = (const fv4*)d_in[4];
    const fv4*   weights4 = (const fv4*)d_in[5];
    const iv4*   patch_i  = (const iv4*)d_in[6];
    const iv4*   inv_i    = (const iv4*)d_in[7];
    const iv4*   src_i    = (const iv4*)d_in[8];
    const iv4*   tgt_i    = (const iv4*)d_in[9];
    fv4*         out      = (fv4*)d_out;

    const size_t local_bytes  = (size_t)N_PATCH * 16;  // f32x4 table
    const size_t poses8_bytes = (size_t)N_POSES * 32;

    if (ws_size >= local_bytes + poses8_bytes) {
        fv4* local4 = (fv4*)d_ws;
        fv4* poses8 = (fv4*)((char*)d_ws + local_bytes);

        hipLaunchKernelGGL(prep_patches, dim3(N_PATCH / 256), dim3(256), 0, stream,
                           (const fv2*)pc_rt, elev, local4);
        hipLaunchKernelGGL(prep_poses, dim3(N_POSES / 256), dim3(256), 0, stream,
                           poses, poses8);
        const int threads = E_EDGES / 4;  // 1,048,576
        hipLaunchKernelGGL(ba_main, dim3(threads / 512), dim3(512), 0, stream,
                           (const fv4*)poses8, (const fv4*)local4, scale,
                           baseline, weights4, patch_i, src_i, tgt_i, out);
    } else {
        const int threads = E_EDGES / 4;
        hipLaunchKernelGGL(ba_fallback, dim3(threads / 256), dim3(256), 0, stream,
                           poses, pc_rt, elev, scale, baseline, weights4,
                           patch_i, inv_i, src_i, tgt_i, out);
    }
}

// Round 8
// 81.435 us; speedup vs baseline: 1.2944x; 1.0191x over previous
//
#include <hip/hip_runtime.h>
#include <math.h>

constexpr int E_EDGES = 4194304;
constexpr int N_PATCH = 524288;
constexpr int N_POSES = 2048;
constexpr float EPS_W = 1e-8f;

typedef int   iv4 __attribute__((ext_vector_type(4)));
typedef float fv4 __attribute__((ext_vector_type(4)));
typedef float fv2 __attribute__((ext_vector_type(2)));

// ---- prep 1: fold r/theta/phi trig into an f32x4 local_src table (16B/patch) ----
// f32 is mandatory: f16 rounding flips atan2's branch cut (round-5 failure, absmax=2pi*sy).
__global__ __launch_bounds__(256) void prep_patches(
    const fv2*  __restrict__ pc_rt,    // N_PATCH x (r,theta)
    const float* __restrict__ elev,    // N_PATCH
    fv4*        __restrict__ local4)   // N_PATCH x (lx,ly,lz,0)
{
    const int j = blockIdx.x * blockDim.x + threadIdx.x;
    if (j >= N_PATCH) return;
    const fv2 pc = pc_rt[j];
    const float phi = elev[j];
    float sphi, cphi, sth, cth;
    __sincosf(phi,  &sphi, &cphi);
    __sincosf(pc.y, &sth,  &cth);
    const float rcp = pc.x * cphi;
    fv4 o;
    o.x = rcp * cth;
    o.y = rcp * sth;
    o.z = pc.x * sphi;
    o.w = 0.0f;
    local4[j] = o;
}

// ---- prep 2: pad poses 7 -> 8 floats ----
__global__ __launch_bounds__(256) void prep_poses(
    const float* __restrict__ poses, fv4* __restrict__ poses8)
{
    const int j = blockIdx.x * blockDim.x + threadIdx.x;
    if (j >= N_POSES) return;
    const float* p = poses + (size_t)j * 7;
    fv4 a, b;
    a.x = p[0]; a.y = p[1]; a.z = p[2]; a.w = p[3];   // px py pz qx
    b.x = p[4]; b.y = p[5]; b.z = p[6]; b.w = 0.0f;   // qy qz qw -
    poses8[2 * j]     = a;
    poses8[2 * j + 1] = b;
}

// ---- main: 1024 thr/block, 64KB LDS -> 2 blocks/CU = 32 waves/CU (100%),
//      4 edges/thread, poses in LDS, 1 divergent VMEM gather per edge ----
__global__ __launch_bounds__(1024, 8) void ba_main(
    const fv4*  __restrict__ poses8,
    const fv4*  __restrict__ local4,
    const float* __restrict__ scale,
    const fv4*  __restrict__ baseline4,
    const fv4*  __restrict__ weights4,
    const iv4*  __restrict__ patch_idx4,
    const iv4*  __restrict__ src_idx4,
    const iv4*  __restrict__ tgt_idx4,
    fv4*        __restrict__ out4)
{
    __shared__ fv4 sposes[N_POSES * 2];   // 64 KB
#pragma unroll
    for (int k = 0; k < (N_POSES * 2) / 1024; ++k)
        sposes[k * 1024 + threadIdx.x] = poses8[k * 1024 + threadIdx.x];
    __syncthreads();

    const int t = blockIdx.x * blockDim.x + threadIdx.x;  // one thread = 4 edges

    const iv4 pi = __builtin_nontemporal_load(patch_idx4 + t);
    const iv4 si = __builtin_nontemporal_load(src_idx4 + t);
    const iv4 ti = __builtin_nontemporal_load(tgt_idx4 + t);

    const fv4 bl01 = __builtin_nontemporal_load(baseline4 + 2 * t);
    const fv4 bl23 = __builtin_nontemporal_load(baseline4 + 2 * t + 1);
    const fv4 w01  = __builtin_nontemporal_load(weights4 + 2 * t);
    const fv4 w23  = __builtin_nontemporal_load(weights4 + 2 * t + 1);

    int pia[4], sia[4], gia[4];
#pragma unroll
    for (int i = 0; i < 4; ++i) {
        pia[i] = ((const int*)&pi)[i];
        sia[i] = ((const int*)&si)[i];
        gia[i] = ((const int*)&ti)[i];
    }

    // issue all 4 divergent table gathers up front (the only VMEM gathers left)
    fv4 L[4];
#pragma unroll
    for (int i = 0; i < 4; ++i) L[i] = local4[pia[i]];
    __builtin_amdgcn_sched_barrier(0);

    const float sx = scale[0];
    const float sy = scale[1];

    float rx[4], ry[4];
#pragma unroll
    for (int i = 0; i < 4; ++i) {
        const float lx = L[i].x, ly = L[i].y, lz = L[i].z;

        const fv4 S0 = sposes[2 * sia[i]];
        const fv4 S1 = sposes[2 * sia[i] + 1];
        const fv4 T0 = sposes[2 * gia[i]];
        const fv4 T1 = sposes[2 * gia[i] + 1];

        const float qx = S0.w, qy = S1.x, qz = S1.y, qw = S1.z;
        const float t0 = 2.0f * (qy * lz - qz * ly);
        const float t1 = 2.0f * (qz * lx - qx * lz);
        const float t2 = 2.0f * (qx * ly - qy * lx);
        const float gx = lx + qw * t0 + (qy * t2 - qz * t1) + S0.x;
        const float gy = ly + qw * t1 + (qz * t0 - qx * t2) + S0.y;
        const float gz = lz + qw * t2 + (qx * t1 - qy * t0) + S0.z;

        const float dx = gx - T0.x;
        const float dy = gy - T0.y;
        const float dz = gz - T0.z;
        const float uqx = -T0.w, uqy = -T1.x, uqz = -T1.y, uqw = T1.z;

        const float u0 = 2.0f * (uqy * dz - uqz * dy);
        const float u1 = 2.0f * (uqz * dx - uqx * dz);
        const float u2 = 2.0f * (uqx * dy - uqy * dx);
        const float ox = dx + uqw * u0 + (uqy * u2 - uqz * u1);
        const float oy = dy + uqw * u1 + (uqz * u0 - uqx * u2);
        const float oz = dz + uqw * u2 + (uqx * u1 - uqy * u0);

        rx[i] = sqrtf(ox * ox + oy * oy + oz * oz) * sx;
        ry[i] = atan2f(oy, ox) * sy;
    }

    // plain stores: partial-line pairs combine in L2 (NT stores caused 2x write amp)
    fv4 o01, o23;
    o01.x = (rx[0] - bl01.x) * sqrtf(w01.x + EPS_W);
    o01.y = (ry[0] - bl01.y) * sqrtf(w01.y + EPS_W);
    o01.z = (rx[1] - bl01.z) * sqrtf(w01.z + EPS_W);
    o01.w = (ry[1] - bl01.w) * sqrtf(w01.w + EPS_W);
    o23.x = (rx[2] - bl23.x) * sqrtf(w23.x + EPS_W);
    o23.y = (ry[2] - bl23.y) * sqrtf(w23.y + EPS_W);
    o23.z = (rx[3] - bl23.z) * sqrtf(w23.z + EPS_W);
    o23.w = (ry[3] - bl23.w) * sqrtf(w23.w + EPS_W);
    out4[2 * t]     = o01;
    out4[2 * t + 1] = o23;
}

// ---- fallback (round-3 proven kernel) if ws is too small ----
__global__ __launch_bounds__(256, 4) void ba_fallback(
    const float* __restrict__ poses,
    const float* __restrict__ pc_rt,
    const float* __restrict__ elev,
    const float* __restrict__ scale,
    const fv4*   __restrict__ baseline4,
    const fv4*   __restrict__ weights4,
    const iv4*   __restrict__ patch_idx4,
    const iv4*   __restrict__ inv_idx4,
    const iv4*   __restrict__ src_idx4,
    const iv4*   __restrict__ tgt_idx4,
    fv4*         __restrict__ out4)
{
    const float sx = scale[0];
    const float sy = scale[1];
    const int t = blockIdx.x * blockDim.x + threadIdx.x;

    const iv4 pi = __builtin_nontemporal_load(patch_idx4 + t);
    const iv4 ii = __builtin_nontemporal_load(inv_idx4 + t);
    const iv4 si = __builtin_nontemporal_load(src_idx4 + t);
    const iv4 ti = __builtin_nontemporal_load(tgt_idx4 + t);

    const fv4 bl01 = __builtin_nontemporal_load(baseline4 + 2 * t);
    const fv4 bl23 = __builtin_nontemporal_load(baseline4 + 2 * t + 1);
    const fv4 w01  = __builtin_nontemporal_load(weights4 + 2 * t);
    const fv4 w23  = __builtin_nontemporal_load(weights4 + 2 * t + 1);

    float rx[4], ry[4];
#pragma unroll
    for (int i = 0; i < 4; ++i) {
        const int p = ((const int*)&pi)[i];
        const int v = ((const int*)&ii)[i];
        const int s = ((const int*)&si)[i];
        const int g = ((const int*)&ti)[i];
        const float r  = pc_rt[2 * (size_t)p];
        const float th = pc_rt[2 * (size_t)p + 1];
        const float phi = elev[v];
        const float* Pp = poses + (size_t)s * 7;
        const float* Tp = poses + (size_t)g * 7;

        float sphi, cphi, sth, cth;
        __sincosf(phi, &sphi, &cphi);
        __sincosf(th,  &sth,  &cth);
        const float rcp = r * cphi;
        const float lx = rcp * cth, ly = rcp * sth, lz = r * sphi;

        const float qx = Pp[3], qy = Pp[4], qz = Pp[5], qw = Pp[6];
        const float t0 = 2.0f * (qy * lz - qz * ly);
        const float t1 = 2.0f * (qz * lx - qx * lz);
        const float t2 = 2.0f * (qx * ly - qy * lx);
        const float gx = lx + qw * t0 + (qy * t2 - qz * t1) + Pp[0];
        const float gy = ly + qw * t1 + (qz * t0 - qx * t2) + Pp[1];
        const float gz = lz + qw * t2 + (qx * t1 - qy * t0) + Pp[2];

        const float dx = gx - Tp[0], dy = gy - Tp[1], dz = gz - Tp[2];
        const float uqx = -Tp[3], uqy = -Tp[4], uqz = -Tp[5], uqw = Tp[6];
        const float u0 = 2.0f * (uqy * dz - uqz * dy);
        const float u1 = 2.0f * (uqz * dx - uqx * dz);
        const float u2 = 2.0f * (uqx * dy - uqy * dx);
        const float ox = dx + uqw * u0 + (uqy * u2 - uqz * u1);
        const float oy = dy + uqw * u1 + (uqz * u0 - uqx * u2);
        const float oz = dz + uqw * u2 + (uqx * u1 - uqy * u0);

        rx[i] = sqrtf(ox * ox + oy * oy + oz * oz) * sx;
        ry[i] = atan2f(oy, ox) * sy;
    }

    fv4 o01, o23;
    o01.x = (rx[0] - bl01.x) * sqrtf(w01.x + EPS_W);
    o01.y = (ry[0] - bl01.y) * sqrtf(w01.y + EPS_W);
    o01.z = (rx[1] - bl01.z) * sqrtf(w01.z + EPS_W);
    o01.w = (ry[1] - bl01.w) * sqrtf(w01.w + EPS_W);
    o23.x = (rx[2] - bl23.x) * sqrtf(w23.x + EPS_W);
    o23.y = (ry[2] - bl23.y) * sqrtf(w23.y + EPS_W);
    o23.z = (rx[3] - bl23.z) * sqrtf(w23.z + EPS_W);
    o23.w = (ry[3] - bl23.w) * sqrtf(w23.w + EPS_W);

    out4[2 * t]     = o01;
    out4[2 * t + 1] = o23;
}

extern "C" void kernel_launch(void* const* d_in, const int* in_sizes, int n_in,
                              void* d_out, int out_size, void* d_ws, size_t ws_size,
                              hipStream_t stream) {
    const float* poses    = (const float*)d_in[0];
    const float* pc_rt    = (const float*)d_in[1];
    const float* elev     = (const float*)d_in[2];
    const float* scale    = (const float*)d_in[3];
    const fv4*   baseline = (const fv4*)d_in[4];
    const fv4*   weights4 = (const fv4*)d_in[5];
    const iv4*   patch_i  = (const iv4*)d_in[6];
    const iv4*   inv_i    = (const iv4*)d_in[7];
    const iv4*   src_i    = (const iv4*)d_in[8];
    const iv4*   tgt_i    = (const iv4*)d_in[9];
    fv4*         out      = (fv4*)d_out;

    const size_t local_bytes  = (size_t)N_PATCH * 16;  // f32x4 table
    const size_t poses8_bytes = (size_t)N_POSES * 32;

    if (ws_size >= local_bytes + poses8_bytes) {
        fv4* local4 = (fv4*)d_ws;
        fv4* poses8 = (fv4*)((char*)d_ws + local_bytes);

        hipLaunchKernelGGL(prep_patches, dim3(N_PATCH / 256), dim3(256), 0, stream,
                           (const fv2*)pc_rt, elev, local4);
        hipLaunchKernelGGL(prep_poses, dim3(N_POSES / 256), dim3(256), 0, stream,
                           poses, poses8);
        const int threads = E_EDGES / 4;  // 1,048,576
        hipLaunchKernelGGL(ba_main, dim3(threads / 1024), dim3(1024), 0, stream,
                           (const fv4*)poses8, (const fv4*)local4, scale,
                           baseline, weights4, patch_i, src_i, tgt_i, out);
    } else {
        const int threads = E_EDGES / 4;
        hipLaunchKernelGGL(ba_fallback, dim3(threads / 256), dim3(256), 0, stream,
                           poses, pc_rt, elev, scale, baseline, weights4,
                           patch_i, inv_i, src_i, tgt_i, out);
    }
}

// Round 9
// 78.760 us; speedup vs baseline: 1.3384x; 1.0340x over previous
//
#include <hip/hip_runtime.h>
#include <math.h>

constexpr int E_EDGES = 4194304;
constexpr int N_PATCH = 524288;
constexpr int N_POSES = 2048;
constexpr float EPS_W = 1e-8f;

typedef int   iv4 __attribute__((ext_vector_type(4)));
typedef float fv4 __attribute__((ext_vector_type(4)));
typedef float fv2 __attribute__((ext_vector_type(2)));

// fast atan2: v_rcp + deg-7 odd minimax on [0,1]; max err ~1.5e-4 rad
// (x0.04 absmax after sy-scaling; budget ~11). Branch-cut sign taken from
// bit-exact oy -> no 2pi flips (round-5 lesson).
__device__ __forceinline__ float fast_atan2f(float y, float x) {
    const float ax = __builtin_fabsf(x);
    const float ay = __builtin_fabsf(y);
    const float mx = fmaxf(ax, ay);
    const float mn = fminf(ax, ay);
    const float z  = mn * __builtin_amdgcn_rcpf(mx);
    const float z2 = z * z;
    float p = fmaf(z2, -0.0851330f, 0.1801410f);
    p = fmaf(z2, p, -0.3302995f);
    p = fmaf(z2, p, 0.9998660f);
    p = p * z;
    p = (ay > ax) ? (1.57079632679f - p) : p;
    p = (x < 0.0f) ? (3.14159265359f - p) : p;
    return __builtin_copysignf(p, y);
}

// ---- fused prep: patch trig table + padded poses in one launch ----
// f32 table is mandatory: f16 rounding flips atan2's branch cut (round-5, absmax=2pi*sy).
__global__ __launch_bounds__(256) void prep_all(
    const fv2*  __restrict__ pc_rt,    // N_PATCH x (r,theta)
    const float* __restrict__ elev,    // N_PATCH
    const float* __restrict__ poses,   // N_POSES x 7
    fv4*        __restrict__ local4,   // N_PATCH x (lx,ly,lz,0)
    fv4*        __restrict__ poses8)   // N_POSES x 2 fv4
{
    const int j = blockIdx.x * blockDim.x + threadIdx.x;
    if (j < N_POSES) {
        const float* p = poses + (size_t)j * 7;
        fv4 a, b;
        a.x = p[0]; a.y = p[1]; a.z = p[2]; a.w = p[3];   // px py pz qx
        b.x = p[4]; b.y = p[5]; b.z = p[6]; b.w = 0.0f;   // qy qz qw -
        poses8[2 * j]     = a;
        poses8[2 * j + 1] = b;
    }
    if (j >= N_PATCH) return;
    const fv2 pc = pc_rt[j];
    const float phi = elev[j];
    float sphi, cphi, sth, cth;
    __sincosf(phi,  &sphi, &cphi);
    __sincosf(pc.y, &sth,  &cth);
    const float rcp = pc.x * cphi;
    fv4 o;
    o.x = rcp * cth;
    o.y = rcp * sth;
    o.z = pc.x * sphi;
    o.w = 0.0f;
    local4[j] = o;
}

// ---- main: 1024 thr/block, 64KB LDS -> 2 blocks/CU = 32 waves/CU,
//      4 edges/thread, poses in LDS, 1 divergent VMEM gather per edge ----
__global__ __launch_bounds__(1024, 8) void ba_main(
    const fv4*  __restrict__ poses8,
    const fv4*  __restrict__ local4,
    const float* __restrict__ scale,
    const fv4*  __restrict__ baseline4,
    const fv4*  __restrict__ weights4,
    const iv4*  __restrict__ patch_idx4,
    const iv4*  __restrict__ src_idx4,
    const iv4*  __restrict__ tgt_idx4,
    fv4*        __restrict__ out4)
{
    __shared__ fv4 sposes[N_POSES * 2];   // 64 KB
#pragma unroll
    for (int k = 0; k < (N_POSES * 2) / 1024; ++k)
        sposes[k * 1024 + threadIdx.x] = poses8[k * 1024 + threadIdx.x];
    __syncthreads();

    const int t = blockIdx.x * blockDim.x + threadIdx.x;  // one thread = 4 edges

    const iv4 pi = __builtin_nontemporal_load(patch_idx4 + t);
    const iv4 si = __builtin_nontemporal_load(src_idx4 + t);
    const iv4 ti = __builtin_nontemporal_load(tgt_idx4 + t);

    const fv4 bl01 = __builtin_nontemporal_load(baseline4 + 2 * t);
    const fv4 bl23 = __builtin_nontemporal_load(baseline4 + 2 * t + 1);
    const fv4 w01  = __builtin_nontemporal_load(weights4 + 2 * t);
    const fv4 w23  = __builtin_nontemporal_load(weights4 + 2 * t + 1);

    int pia[4], sia[4], gia[4];
#pragma unroll
    for (int i = 0; i < 4; ++i) {
        pia[i] = ((const int*)&pi)[i];
        sia[i] = ((const int*)&si)[i];
        gia[i] = ((const int*)&ti)[i];
    }

    // issue all 4 divergent table gathers up front (the only VMEM gathers left)
    fv4 L[4];
#pragma unroll
    for (int i = 0; i < 4; ++i) L[i] = local4[pia[i]];
    __builtin_amdgcn_sched_barrier(0);

    const float sx = scale[0];
    const float sy = scale[1];

    float rx[4], ry[4];
#pragma unroll
    for (int i = 0; i < 4; ++i) {
        const float lx = L[i].x, ly = L[i].y, lz = L[i].z;

        const fv4 S0 = sposes[2 * sia[i]];
        const fv4 S1 = sposes[2 * sia[i] + 1];
        const fv4 T0 = sposes[2 * gia[i]];
        const fv4 T1 = sposes[2 * gia[i] + 1];

        const float qx = S0.w, qy = S1.x, qz = S1.y, qw = S1.z;
        const float t0 = 2.0f * (qy * lz - qz * ly);
        const float t1 = 2.0f * (qz * lx - qx * lz);
        const float t2 = 2.0f * (qx * ly - qy * lx);
        const float gx = lx + qw * t0 + (qy * t2 - qz * t1) + S0.x;
        const float gy = ly + qw * t1 + (qz * t0 - qx * t2) + S0.y;
        const float gz = lz + qw * t2 + (qx * t1 - qy * t0) + S0.z;

        const float dx = gx - T0.x;
        const float dy = gy - T0.y;
        const float dz = gz - T0.z;
        const float uqx = -T0.w, uqy = -T1.x, uqz = -T1.y, uqw = T1.z;

        const float u0 = 2.0f * (uqy * dz - uqz * dy);
        const float u1 = 2.0f * (uqz * dx - uqx * dz);
        const float u2 = 2.0f * (uqx * dy - uqy * dx);
        const float ox = dx + uqw * u0 + (uqy * u2 - uqz * u1);
        const float oy = dy + uqw * u1 + (uqz * u0 - uqx * u2);
        const float oz = dz + uqw * u2 + (uqx * u1 - uqy * u0);

        rx[i] = __builtin_amdgcn_sqrtf(ox * ox + oy * oy + oz * oz) * sx;
        ry[i] = fast_atan2f(oy, ox) * sy;
    }

    // plain stores: partial-line pairs combine in L2 (NT stores caused 2x write amp)
    fv4 o01, o23;
    o01.x = (rx[0] - bl01.x) * __builtin_amdgcn_sqrtf(w01.x + EPS_W);
    o01.y = (ry[0] - bl01.y) * __builtin_amdgcn_sqrtf(w01.y + EPS_W);
    o01.z = (rx[1] - bl01.z) * __builtin_amdgcn_sqrtf(w01.z + EPS_W);
    o01.w = (ry[1] - bl01.w) * __builtin_amdgcn_sqrtf(w01.w + EPS_W);
    o23.x = (rx[2] - bl23.x) * __builtin_amdgcn_sqrtf(w23.x + EPS_W);
    o23.y = (ry[2] - bl23.y) * __builtin_amdgcn_sqrtf(w23.y + EPS_W);
    o23.z = (rx[3] - bl23.z) * __builtin_amdgcn_sqrtf(w23.z + EPS_W);
    o23.w = (ry[3] - bl23.w) * __builtin_amdgcn_sqrtf(w23.w + EPS_W);
    out4[2 * t]     = o01;
    out4[2 * t + 1] = o23;
}

// ---- fallback (round-3 proven kernel) if ws is too small ----
__global__ __launch_bounds__(256, 4) void ba_fallback(
    const float* __restrict__ poses,
    const float* __restrict__ pc_rt,
    const float* __restrict__ elev,
    const float* __restrict__ scale,
    const fv4*   __restrict__ baseline4,
    const fv4*   __restrict__ weights4,
    const iv4*   __restrict__ patch_idx4,
    const iv4*   __restrict__ inv_idx4,
    const iv4*   __restrict__ src_idx4,
    const iv4*   __restrict__ tgt_idx4,
    fv4*         __restrict__ out4)
{
    const float sx = scale[0];
    const float sy = scale[1];
    const int t = blockIdx.x * blockDim.x + threadIdx.x;

    const iv4 pi = __builtin_nontemporal_load(patch_idx4 + t);
    const iv4 ii = __builtin_nontemporal_load(inv_idx4 + t);
    const iv4 si = __builtin_nontemporal_load(src_idx4 + t);
    const iv4 ti = __builtin_nontemporal_load(tgt_idx4 + t);

    const fv4 bl01 = __builtin_nontemporal_load(baseline4 + 2 * t);
    const fv4 bl23 = __builtin_nontemporal_load(baseline4 + 2 * t + 1);
    const fv4 w01  = __builtin_nontemporal_load(weights4 + 2 * t);
    const fv4 w23  = __builtin_nontemporal_load(weights4 + 2 * t + 1);

    float rx[4], ry[4];
#pragma unroll
    for (int i = 0; i < 4; ++i) {
        const int p = ((const int*)&pi)[i];
        const int v = ((const int*)&ii)[i];
        const int s = ((const int*)&si)[i];
        const int g = ((const int*)&ti)[i];
        const float r  = pc_rt[2 * (size_t)p];
        const float th = pc_rt[2 * (size_t)p + 1];
        const float phi = elev[v];
        const float* Pp = poses + (size_t)s * 7;
        const float* Tp = poses + (size_t)g * 7;

        float sphi, cphi, sth, cth;
        __sincosf(phi, &sphi, &cphi);
        __sincosf(th,  &sth,  &cth);
        const float rcp = r * cphi;
        const float lx = rcp * cth, ly = rcp * sth, lz = r * sphi;

        const float qx = Pp[3], qy = Pp[4], qz = Pp[5], qw = Pp[6];
        const float t0 = 2.0f * (qy * lz - qz * ly);
        const float t1 = 2.0f * (qz * lx - qx * lz);
        const float t2 = 2.0f * (qx * ly - qy * lx);
        const float gx = lx + qw * t0 + (qy * t2 - qz * t1) + Pp[0];
        const float gy = ly + qw * t1 + (qz * t0 - qx * t2) + Pp[1];
        const float gz = lz + qw * t2 + (qx * t1 - qy * t0) + Pp[2];

        const float dx = gx - Tp[0], dy = gy - Tp[1], dz = gz - Tp[2];
        const float uqx = -Tp[3], uqy = -Tp[4], uqz = -Tp[5], uqw = Tp[6];
        const float u0 = 2.0f * (uqy * dz - uqz * dy);
        const float u1 = 2.0f * (uqz * dx - uqx * dz);
        const float u2 = 2.0f * (uqx * dy - uqy * dx);
        const float ox = dx + uqw * u0 + (uqy * u2 - uqz * u1);
        const float oy = dy + uqw * u1 + (uqz * u0 - uqx * u2);
        const float oz = dz + uqw * u2 + (uqx * u1 - uqy * u0);

        rx[i] = sqrtf(ox * ox + oy * oy + oz * oz) * sx;
        ry[i] = atan2f(oy, ox) * sy;
    }

    fv4 o01, o23;
    o01.x = (rx[0] - bl01.x) * sqrtf(w01.x + EPS_W);
    o01.y = (ry[0] - bl01.y) * sqrtf(w01.y + EPS_W);
    o01.z = (rx[1] - bl01.z) * sqrtf(w01.z + EPS_W);
    o01.w = (ry[1] - bl01.w) * sqrtf(w01.w + EPS_W);
    o23.x = (rx[2] - bl23.x) * sqrtf(w23.x + EPS_W);
    o23.y = (ry[2] - bl23.y) * sqrtf(w23.y + EPS_W);
    o23.z = (rx[3] - bl23.z) * sqrtf(w23.z + EPS_W);
    o23.w = (ry[3] - bl23.w) * sqrtf(w23.w + EPS_W);

    out4[2 * t]     = o01;
    out4[2 * t + 1] = o23;
}

extern "C" void kernel_launch(void* const* d_in, const int* in_sizes, int n_in,
                              void* d_out, int out_size, void* d_ws, size_t ws_size,
                              hipStream_t stream) {
    const float* poses    = (const float*)d_in[0];
    const float* pc_rt    = (const float*)d_in[1];
    const float* elev     = (const float*)d_in[2];
    const float* scale    = (const float*)d_in[3];
    const fv4*   baseline = (const fv4*)d_in[4];
    const fv4*   weights4 = (const fv4*)d_in[5];
    const iv4*   patch_i  = (const iv4*)d_in[6];
    const iv4*   inv_i    = (const iv4*)d_in[7];
    const iv4*   src_i    = (const iv4*)d_in[8];
    const iv4*   tgt_i    = (const iv4*)d_in[9];
    fv4*         out      = (fv4*)d_out;

    const size_t local_bytes  = (size_t)N_PATCH * 16;  // f32x4 table
    const size_t poses8_bytes = (size_t)N_POSES * 32;

    if (ws_size >= local_bytes + poses8_bytes) {
        fv4* local4 = (fv4*)d_ws;
        fv4* poses8 = (fv4*)((char*)d_ws + local_bytes);

        hipLaunchKernelGGL(prep_all, dim3(N_PATCH / 256), dim3(256), 0, stream,
                           (const fv2*)pc_rt, elev, poses, local4, poses8);
        const int threads = E_EDGES / 4;  // 1,048,576
        hipLaunchKernelGGL(ba_main, dim3(threads / 1024), dim3(1024), 0, stream,
                           (const fv4*)poses8, (const fv4*)local4, scale,
                           baseline, weights4, patch_i, src_i, tgt_i, out);
    } else {
        const int threads = E_EDGES / 4;
        hipLaunchKernelGGL(ba_fallback, dim3(threads / 256), dim3(256), 0, stream,
                           poses, pc_rt, elev, scale, baseline, weights4,
                           patch_i, inv_i, src_i, tgt_i, out);
    }
}